// Round 13
// baseline (104.683 us; speedup 1.0000x reference)
//
#include <hip/hip_runtime.h>

typedef __bf16 bf16;
typedef __attribute__((ext_vector_type(8))) __bf16 bf16x8;
typedef __attribute__((ext_vector_type(4))) __bf16 bf16x4;
typedef __attribute__((ext_vector_type(4))) float f32x4;
typedef __attribute__((ext_vector_type(16))) float f32x16;
typedef __attribute__((ext_vector_type(4))) unsigned u32x4;

#define MFMA16(a, b, c) __builtin_amdgcn_mfma_f32_16x16x32_bf16(a, b, c, 0, 0, 0)
#define MFMA32(a, b, c) __builtin_amdgcn_mfma_f32_32x32x16_bf16(a, b, c, 0, 0, 0)

__device__ inline void gload_lds16(const void* g, void* l) {
  __builtin_amdgcn_global_load_lds(
      (const __attribute__((address_space(1))) void*)g,
      (__attribute__((address_space(3))) void*)l, 16, 0, 0);
}

__device__ inline unsigned packbf(float a, float b) {
  unsigned short x = __builtin_bit_cast(unsigned short, (bf16)a);
  unsigned short y = __builtin_bit_cast(unsigned short, (bf16)b);
  return (unsigned)x | ((unsigned)y << 16);
}

// ---------------------------------------------------------------------------
// prep_W: Wqkvt[768][256], Woutt[256][256] = bf16(W^T)
// ---------------------------------------------------------------------------
__global__ __launch_bounds__(256) void prep_w_kernel(
    const float* __restrict__ Wqkv, const float* __restrict__ Wout,
    bf16* __restrict__ Wqkvt, bf16* __restrict__ Woutt)
{
  int tid = blockIdx.x * 256 + threadIdx.x;
  int nth = gridDim.x * 256;
  for (int i = tid; i < 768 * 256; i += nth) {
    int n = i >> 8, k = i & 255;
    Wqkvt[i] = (bf16)Wqkv[k * 768 + n];
  }
  for (int i = tid; i < 256 * 256; i += nth) {
    int n = i >> 8, k = i & 255;
    Woutt[i] = (bf16)Wout[k * 256 + n];
  }
}

// ---------------------------------------------------------------------------
// GEMM (QKV proj), A-RESIDENT: each block owns 64 rows of concat(prev_x,x),
// stages them ONCE (f32->bf16, 32 KB LDS, XOR-swizzled), then loops over its
// live 256-wide output panels (Q only when s>=2048, K, V) x 8 k-steps,
// streaming W tiles via double-buffered global_load_lds (pre-swizzled source,
// one barrier per step — the verified out_kernel pattern).
// Frag-order outputs (byte-identical formulas to R12-verified):
//   Qp  [qg][ks 16][lane 64][e 8]   (q = qg*32+(lane&31), prescaled 1/16)
//   KVp [b*128+T][ K: ks*512 | V: 8192+(s*8+dg)*512 ][lane*8+e]
// ---------------------------------------------------------------------------
__global__ __launch_bounds__(256) void gemm_qkv_kernel(
    const float* __restrict__ x, const float* __restrict__ px,
    const bf16* __restrict__ Wt, const float* __restrict__ bias,
    bf16* __restrict__ Qo, bf16* __restrict__ KVo)
{
  const int bi = blockIdx.x;          // 256 blocks = 1/CU
  const int b = bi >> 6;
  const int mblk = bi & 63;
  const bool mhalf = mblk >= 32;      // rows s>=2048: Q panel live
  const int bm = b * 4096 + mblk * 64;
  const int s_local = (mblk & 31) * 64;
  const float* xsrc = mhalf ? x : px;
  const size_t xbase = ((size_t)b << 19) + (size_t)s_local * 256;

  const int tid = threadIdx.x;
  const int lane = tid & 63, w = tid >> 6;
  const int l15 = lane & 15, lg = lane >> 4;

  alignas(16) __shared__ bf16 Alds[64 * 256];     // 32 KB, swz ^((row&7)<<4)
  alignas(16) __shared__ bf16 Wlds[2][256 * 32];  // 2 x 16 KB dbuf

  const int ystart = mhalf ? 0 : 1;
  const int nseq = mhalf ? 24 : 16;

  auto stageW = [&](int i) {          // panel/k-step i of the sequence
    const int y = ystart + (i >> 3);
    const int k0 = (i & 7) * 32;
    #pragma unroll
    for (int jj = 0; jj < 4; jj++) {
      int j = w * 4 + jj;             // 16 x 1KB DMA instrs
      int row = j * 16 + (lane >> 2);
      int chunk = (lane & 3) ^ ((row >> 1) & 3);
      const bf16* g = Wt + (size_t)(y * 256 + row) * 256 + k0 + chunk * 8;
      gload_lds16(g, (char*)&Wlds[i & 1][0] + j * 1024);
    }
  };
  stageW(0);

  // stage A once: 64 rows x 256 cols f32 -> bf16
  #pragma unroll
  for (int it = 0; it < 8; it++) {
    int c = it * 256 + tid;           // 2048 chunks of 8 elems
    int row = c >> 5, ch = c & 31;
    const float* src = xsrc + xbase + (size_t)row * 256 + ch * 8;
    float4 f0 = *(const float4*)src;
    float4 f1 = *(const float4*)(src + 4);
    bf16x8 v = { (bf16)f0.x, (bf16)f0.y, (bf16)f0.z, (bf16)f0.w,
                 (bf16)f1.x, (bf16)f1.y, (bf16)f1.z, (bf16)f1.w };
    *(bf16x8*)((char*)Alds + ((c << 4) ^ ((row & 7) << 4))) = v;
  }
  __syncthreads();                    // A written, W(0) landed

  f32x4 acc[16] = {};
  for (int i = 0; i < nseq; i++) {
    if (i + 1 < nseq) stageW(i + 1);
    const int k0 = (i & 7) * 32;
    const bf16* wbuf = &Wlds[i & 1][0];
    const int arow = w * 16 + l15;
    bf16x8 afr = *(const bf16x8*)((char*)Alds +
        ((arow * 512 + k0 * 2 + lg * 16) ^ ((arow & 7) << 4)));
    #pragma unroll
    for (int nt = 0; nt < 16; nt++) {
      const int wrow = nt * 16 + l15;
      bf16x8 bfr = *(const bf16x8*)((char*)wbuf +
          (((wrow << 6) + (lg << 4)) ^ (((wrow >> 1) & 3) << 4)));
      acc[nt] = MFMA16(afr, bfr, acc[nt]);
    }
    __syncthreads();                  // W(i+1) landed; wbuf reads complete

    if ((i & 7) == 7) {               // panel y complete -> epilogue
      const int y = ystart + (i >> 3);
      const int m0 = bm + w * 16 + lg * 4;
      const int bq = m0 >> 12, s = m0 & 4095;
      #pragma unroll
      for (int nt = 0; nt < 16; nt++) {
        const int n = nt * 16 + l15;  // 0..255 within panel
        const float bv = bias[y * 256 + n];
        if (y == 0) {                 // Q (s>=2048 guaranteed)
          const int ks = n >> 4, h2 = (n >> 3) & 1, e = n & 7;
          #pragma unroll
          for (int rr = 0; rr < 4; rr++) {
            const int qrow = bq * 2048 + (s - 2048) + rr;
            Qo[(size_t)(qrow >> 5) * 8192 + ks * 512 +
               ((qrow & 31) + 32 * h2) * 8 + e] =
                (bf16)((acc[nt][rr] + bv) * 0.0625f);
          }
        } else if (y == 1) {          // K
          const int d = n;
          const int ks = d >> 4, h2 = (d >> 3) & 1, e = d & 7;
          const size_t tb = (size_t)(bq * 128 + (s >> 5)) * 16384;
          #pragma unroll
          for (int rr = 0; rr < 4; rr++)
            KVo[tb + ks * 512 + (((s & 31) + rr) + 32 * h2) * 8 + e] =
                (bf16)(acc[nt][rr] + bv);
        } else {                      // V
          const int d = n;
          const int kv32 = s & 31;
          const int sidx = kv32 >> 4, h2 = (kv32 >> 3) & 1, e0 = kv32 & 7;
          bf16x4 st = { (bf16)(acc[nt][0] + bv), (bf16)(acc[nt][1] + bv),
                        (bf16)(acc[nt][2] + bv), (bf16)(acc[nt][3] + bv) };
          *(bf16x4*)(KVo + (size_t)(bq * 128 + (s >> 5)) * 16384 + 8192 +
                     (sidx * 8 + (d >> 5)) * 512 + ((d & 31) + 32 * h2) * 8 + e0) = st;
        }
        acc[nt] = (f32x4){};
      }
    }
  }
}

// ---------------------------------------------------------------------------
// flash attention (R7-verified, 52.8 us): 32x32x16 MFMA, q=32/wave, 4 waves.
// KV-split 8 -> 512 blocks. Fragment-ordered global K/V -> linear
// global_load_lds staging (dbuf), conflict-free lane-linear ds_read_b128.
// Swapped QK^T (S^T = mfma(K,Q)); P B-frags via pack + shfl_xor(32) exchange.
// ---------------------------------------------------------------------------
__global__ __launch_bounds__(256, 2) void attn_kernel(
    const bf16* __restrict__ Qp, const bf16* __restrict__ KVp,
    bf16* __restrict__ Opart, float* __restrict__ ml)
{
  const int id = blockIdx.x;
  const int c = id & 7;            // kv chunk -> XCD affinity (id%8)
  const int b = (id >> 3) & 3;     // batch
  const int qb = id >> 5;          // q block 0..15
  const int tid = threadIdx.x;
  const int lane = tid & 63, w = tid >> 6;
  const int l31 = lane & 31, hi = lane >> 5;

  __shared__ bf16 lds[2][16384];   // [buf][ K frags 0..8191 | V frags 8192.. ]

  const int qg = b * 64 + qb * 4 + w;
  const bf16* qbase = Qp + (size_t)qg * 8192 + lane * 8;
  bf16x8 qf[16];
  #pragma unroll
  for (int ks = 0; ks < 16; ks++)
    qf[ks] = *(const bf16x8*)(qbase + ks * 512);

  const bf16* kvtile0 = KVp + (size_t)(b * 128 + c * 16) * 16384;

  auto stage = [&](int t) {
    const char* g = (const char*)(kvtile0 + (size_t)t * 16384) + w * 8192 + lane * 16;
    char* l = (char*)&lds[t & 1][0] + w * 8192;
    #pragma unroll
    for (int j = 0; j < 8; j++)
      gload_lds16(g + j * 1024, l + j * 1024);
  };
  stage(0);

  f32x16 o[8] = {};                // O^T[d][q]: q = l31, d = dg*32+8*(r>>2)+4*hi+(r&3)
  float m_run = -1e30f, l_run = 0.f;

  for (int t = 0; t < 16; t++) {
    __syncthreads();               // tile t landed; buf^1 free
    if (t + 1 < 16) stage(t + 1);
    const bf16* kbuf = &lds[t & 1][0];
    const bf16* vbuf = kbuf + 8192;

    f32x16 p = {};
    __builtin_amdgcn_s_setprio(1);
    #pragma unroll
    for (int ks = 0; ks < 16; ks++) {
      bf16x8 kf = *(const bf16x8*)(kbuf + ks * 512 + lane * 8);
      p = MFMA32(kf, qf[ks], p);
    }
    __builtin_amdgcn_s_setprio(0);

    float mt = fmaxf(p[0], p[1]);
    #pragma unroll
    for (int i = 2; i < 16; i++) mt = fmaxf(mt, p[i]);
    mt = fmaxf(mt, __shfl_xor(mt, 32));
    if (!__all(mt <= m_run + 8.f)) {   // defer-max (T13)
      const float m_new = fmaxf(m_run, mt);
      const float alpha = __expf(m_run - m_new);
      l_run *= alpha;
      #pragma unroll
      for (int i = 0; i < 8; i++)
        #pragma unroll
        for (int j = 0; j < 16; j++) o[i][j] *= alpha;
      m_run = m_new;
    }
    float ps = 0.f;
    #pragma unroll
    for (int i = 0; i < 16; i++) { p[i] = __expf(p[i] - m_run); ps += p[i]; }
    ps += __shfl_xor(ps, 32);
    l_run += ps;

    // P -> B-frags (verified mapping)
    unsigned u[8], xp[8];
    #pragma unroll
    for (int i = 0; i < 8; i++) u[i] = packbf(p[2 * i], p[2 * i + 1]);
    #pragma unroll
    for (int i = 0; i < 8; i++)
      xp[i] = (unsigned)__shfl_xor((int)u[i], 32);
    const u32x4 w0 = hi ? (u32x4){xp[2], xp[3], u[2], u[3]}
                        : (u32x4){u[0], u[1], xp[0], xp[1]};
    const u32x4 w1 = hi ? (u32x4){xp[6], xp[7], u[6], u[7]}
                        : (u32x4){u[4], u[5], xp[4], xp[5]};
    const bf16x8 pf0 = __builtin_bit_cast(bf16x8, w0);
    const bf16x8 pf1 = __builtin_bit_cast(bf16x8, w1);

    __builtin_amdgcn_s_setprio(1);
    #pragma unroll
    for (int dg = 0; dg < 8; dg++) {
      bf16x8 v0 = *(const bf16x8*)(vbuf + dg * 512 + lane * 8);
      o[dg] = MFMA32(v0, pf0, o[dg]);
      bf16x8 v1 = *(const bf16x8*)(vbuf + (8 + dg) * 512 + lane * 8);
      o[dg] = MFMA32(v1, pf1, o[dg]);
    }
    __builtin_amdgcn_s_setprio(0);
  }

  const int q = b * 2048 + qb * 128 + w * 32 + l31;
  bf16* ob = Opart + ((size_t)c * 8192 + q) * 256;
  #pragma unroll
  for (int dg = 0; dg < 8; dg++) {
    #pragma unroll
    for (int r4 = 0; r4 < 4; r4++) {
      const int d = dg * 32 + r4 * 8 + hi * 4;
      bf16x4 st = { (bf16)o[dg][r4 * 4 + 0], (bf16)o[dg][r4 * 4 + 1],
                    (bf16)o[dg][r4 * 4 + 2], (bf16)o[dg][r4 * 4 + 3] };
      *(bf16x4*)(ob + d) = st;
    }
  }
  if (hi == 0) {
    float2 v = { m_run, l_run };
    *(float2*)(ml + ((size_t)c * 8192 + q) * 2) = v;
  }
}

// ---------------------------------------------------------------------------
// fused combine + out-proj (R12-verified): combine(Opart, ml) -> Alds
// (32x256, XOR-swz), then C = A @ Woutt^T + bout; W dbuf via global_load_lds.
// ---------------------------------------------------------------------------
__global__ __launch_bounds__(256) void out_kernel(
    const bf16* __restrict__ Opart, const float* __restrict__ ml,
    const bf16* __restrict__ Woutt, const float* __restrict__ bout,
    float* __restrict__ out)
{
  const int bm = blockIdx.x * 32;   // 256 blocks
  const int tid = threadIdx.x;
  const int lane = tid & 63, w = tid >> 6;
  const int l15 = lane & 15, lg = lane >> 4;

  alignas(16) __shared__ bf16 Alds[32 * 256];     // 16 KB, swz ^((row&7)<<4)
  alignas(16) __shared__ bf16 Wlds[2][256 * 32];  // 2 x 16 KB dbuf

  auto stageW = [&](int k0) {
    #pragma unroll
    for (int jj = 0; jj < 4; jj++) {
      int j = w * 4 + jj;                    // 16 x 1KB instrs
      int row = j * 16 + (lane >> 2);
      int chunk = (lane & 3) ^ ((row >> 1) & 3);
      const bf16* g = Woutt + (size_t)row * 256 + k0 * 32 + chunk * 8;
      gload_lds16(g, (char*)&Wlds[k0 & 1][0] + j * 1024);
    }
  };
  stageW(0);

  // combine 8 partials -> Alds
  #pragma unroll
  for (int ch = 0; ch < 4; ch++) {
    const int idx = ch * 256 + tid;
    const int row = idx >> 5;
    const int dc = (idx & 31) << 3;
    const int q = bm + row;
    float ms[8], ls[8], M = -1e30f;
    #pragma unroll
    for (int s = 0; s < 8; s++) {
      float2 v = *(const float2*)(ml + ((size_t)s * 8192 + q) * 2);
      ms[s] = v.x; ls[s] = v.y;
      M = fmaxf(M, v.x);
    }
    float L = 0.f, acc[8] = {};
    #pragma unroll
    for (int s = 0; s < 8; s++) {
      const float wgt = __expf(ms[s] - M);
      L += ls[s] * wgt;
      bf16x8 v = *(const bf16x8*)(Opart + ((size_t)s * 8192 + q) * 256 + dc);
      #pragma unroll
      for (int j = 0; j < 8; j++) acc[j] += wgt * (float)v[j];
    }
    const float inv = 1.f / L;
    bf16x8 st;
    #pragma unroll
    for (int j = 0; j < 8; j++) st[j] = (bf16)(acc[j] * inv);
    *(bf16x8*)((char*)Alds + ((row * 512 + dc * 2) ^ ((row & 7) << 4))) = st;
  }
  __syncthreads();   // Alds written, W(0) landed

  f32x4 acc[8] = {};
  for (int k0 = 0; k0 < 8; k0++) {
    if (k0 + 1 < 8) stageW(k0 + 1);
    const bf16* wbuf = &Wlds[k0 & 1][0];
    const int arow = (w & 1) * 16 + l15;
    bf16x8 afr = *(const bf16x8*)((char*)Alds +
        ((arow * 512 + k0 * 64 + lg * 16) ^ ((arow & 7) << 4)));
    #pragma unroll
    for (int nt = 0; nt < 8; nt++) {
      const int wrow = (w >> 1) * 128 + nt * 16 + l15;
      bf16x8 bfr = *(const bf16x8*)((char*)wbuf +
          (((wrow << 6) + (lg << 4)) ^ (((wrow >> 1) & 3) << 4)));
      acc[nt] = MFMA16(afr, bfr, acc[nt]);
    }
    __syncthreads();   // W(k0+1) landed; buf reads done before overwrite
  }

  #pragma unroll
  for (int nt = 0; nt < 8; nt++) {
    const int n = (w >> 1) * 128 + nt * 16 + l15;
    const float bvv = bout[n];
    const int m0 = bm + (w & 1) * 16 + lg * 4;
    #pragma unroll
    for (int r = 0; r < 4; r++)
      out[(size_t)(m0 + r) * 256 + n] = acc[nt][r] + bvv;
  }
}

// ---------------------------------------------------------------------------
extern "C" void kernel_launch(void* const* d_in, const int* in_sizes, int n_in,
                              void* d_out, int out_size, void* d_ws, size_t ws_size,
                              hipStream_t stream) {
  const float* x    = (const float*)d_in[0];
  const float* px   = (const float*)d_in[1];
  const float* Wqkv = (const float*)d_in[2];
  const float* bqkv = (const float*)d_in[3];
  const float* Wout = (const float*)d_in[4];
  const float* bout = (const float*)d_in[5];
  float* out = (float*)d_out;

  char* ws = (char*)d_ws;
  bf16* Qp    = (bf16*)(ws);                    //  4 MB frag-ordered Q (*1/16)
  bf16* KVp   = (bf16*)(ws + 4194304);          // 16 MB frag-ordered K|V tiles
  bf16* Woutt = (bf16*)(ws + 20971520);         // 128 KB
  bf16* Wqkvt = (bf16*)(ws + 21102592);         // 384 KB
  float* ml   = (float*)(ws + 21495808);        // 512 KB [8][8192][2]
  bf16* Opart = (bf16*)(ws + 22020096);         // 32 MB [8][8192][256]

  prep_w_kernel<<<dim3(128), dim3(256), 0, stream>>>(Wqkv, Wout, Wqkvt, Woutt);
  gemm_qkv_kernel<<<dim3(256), dim3(256), 0, stream>>>(
      x, px, Wqkvt, bqkv, Qp, KVp);
  attn_kernel<<<dim3(512), dim3(256), 0, stream>>>(Qp, KVp, Opart, ml);
  out_kernel<<<dim3(256), dim3(256), 0, stream>>>(Opart, ml, Woutt, bout, out);
}

// Round 14
// 88.850 us; speedup vs baseline: 1.1782x; 1.1782x over previous
//
#include <hip/hip_runtime.h>

typedef __bf16 bf16;
typedef __attribute__((ext_vector_type(8))) __bf16 bf16x8;
typedef __attribute__((ext_vector_type(4))) __bf16 bf16x4;
typedef __attribute__((ext_vector_type(4))) float f32x4;
typedef __attribute__((ext_vector_type(16))) float f32x16;
typedef __attribute__((ext_vector_type(4))) unsigned u32x4;

#define MFMA16(a, b, c) __builtin_amdgcn_mfma_f32_16x16x32_bf16(a, b, c, 0, 0, 0)
#define MFMA32(a, b, c) __builtin_amdgcn_mfma_f32_32x32x16_bf16(a, b, c, 0, 0, 0)

__device__ inline void gload_lds16(const void* g, void* l) {
  __builtin_amdgcn_global_load_lds(
      (const __attribute__((address_space(1))) void*)g,
      (__attribute__((address_space(3))) void*)l, 16, 0, 0);
}

__device__ inline unsigned packbf(float a, float b) {
  unsigned short x = __builtin_bit_cast(unsigned short, (bf16)a);
  unsigned short y = __builtin_bit_cast(unsigned short, (bf16)b);
  return (unsigned)x | ((unsigned)y << 16);
}

// ---------------------------------------------------------------------------
// prep_W: Wqkvt[768][256], Woutt[256][256] = bf16(W^T)
// ---------------------------------------------------------------------------
__global__ __launch_bounds__(256) void prep_w_kernel(
    const float* __restrict__ Wqkv, const float* __restrict__ Wout,
    bf16* __restrict__ Wqkvt, bf16* __restrict__ Woutt)
{
  int tid = blockIdx.x * 256 + threadIdx.x;
  int nth = gridDim.x * 256;
  for (int i = tid; i < 768 * 256; i += nth) {
    int n = i >> 8, k = i & 255;
    Wqkvt[i] = (bf16)Wqkv[k * 768 + n];
  }
  for (int i = tid; i < 256 * 256; i += nth) {
    int n = i >> 8, k = i & 255;
    Woutt[i] = (bf16)Wout[k * 256 + n];
  }
}

// ---------------------------------------------------------------------------
// GEMM (QKV proj): C = concat(prev_x,x)[16384][256] @ Wt[768][256]^T + bias.
// R12 structure (two-barrier k-loop, DMA'd W, packed live grid, >=2 blk/CU)
// with BM=64 x BN=256, ONE panel y per block: A re-read drops to 2-3x/row
// (40 MB), epilogue is panel-uniform. 640 blocks.
// Frag-order outputs (byte-identical formulas, verified R12/R13):
//   Qp  [qg][ks 16][lane 64][e 8]   (q = qg*32+(lane&31), prescaled 1/16)
//   KVp [b*128+T][ K: ks*512 | V: 8192+(s*8+dg)*512 ][lane*8+e]
// ---------------------------------------------------------------------------
__global__ __launch_bounds__(256) void gemm_qkv_kernel(
    const float* __restrict__ x, const float* __restrict__ px,
    const bf16* __restrict__ Wt, const float* __restrict__ bias,
    bf16* __restrict__ Qo, bf16* __restrict__ KVo)
{
  // packed grid: per batch 160 blocks = 32 low m-blocks x {K,V} + 32 high x {Q,K,V}
  const int idb = blockIdx.x;
  const int b = idb / 160;
  const int r = idb % 160;
  int mblk, y;
  if (r < 64) { mblk = r >> 1; y = 1 + (r & 1); }
  else { int r2 = r - 64; mblk = 32 + r2 / 3; y = r2 % 3; }
  const int bm = b * 4096 + mblk * 64;

  const int tid = threadIdx.x;
  const int lane = tid & 63, w = tid >> 6;
  const int l15 = lane & 15, lg = lane >> 4;

  alignas(16) __shared__ bf16 Alds[64 * 32];    // 4 KB per k-step
  alignas(16) __shared__ bf16 Wlds[256 * 32];   // 16 KB per k-step

  f32x4 acc[16] = {};

  const float* xsrc = (mblk >= 32) ? x : px;
  const size_t xbase = ((size_t)b << 19) + (size_t)((mblk & 31) * 64) * 256;

  for (int k0 = 0; k0 < 256; k0 += 32) {
    __syncthreads();
    {   // A tile 64x32 f32 -> bf16 (1 chunk/thread), XOR-swizzled (R12 path)
      int c = tid;
      int row = c >> 2, kc = (c & 3) << 3;
      const float* src = xsrc + xbase + (size_t)row * 256 + k0 + kc;
      float4 f0 = *(const float4*)src;
      float4 f1 = *(const float4*)(src + 4);
      bf16x8 v = { (bf16)f0.x, (bf16)f0.y, (bf16)f0.z, (bf16)f0.w,
                   (bf16)f1.x, (bf16)f1.y, (bf16)f1.z, (bf16)f1.w };
      *(bf16x8*)((char*)Alds + ((c << 4) ^ (((row >> 1) & 3) << 4))) = v;
    }
    #pragma unroll
    for (int jj = 0; jj < 4; jj++) {  // W tile 256x32 via DMA, pre-swizzled src
      int j = w * 4 + jj;             // 16 x 1KB instrs (verified R12/R13)
      int row = j * 16 + (lane >> 2);
      int chunk = (lane & 3) ^ ((row >> 1) & 3);
      const bf16* g = Wt + (size_t)(y * 256 + row) * 256 + k0 + chunk * 8;
      gload_lds16(g, (char*)Wlds + j * 1024);
    }
    __syncthreads();

    const int arow = w * 16 + l15;
    bf16x8 afr = *(const bf16x8*)((char*)Alds +
        (((arow << 6) + (lg << 4)) ^ (((arow >> 1) & 3) << 4)));
    #pragma unroll
    for (int nt = 0; nt < 16; nt++) {
      const int wrow = nt * 16 + l15;
      bf16x8 bfr = *(const bf16x8*)((char*)Wlds +
          (((wrow << 6) + (lg << 4)) ^ (((wrow >> 1) & 3) << 4)));
      acc[nt] = MFMA16(afr, bfr, acc[nt]);
    }
  }

  // panel-uniform epilogue (formulas byte-identical to R12/R13 verified)
  const int m0 = bm + w * 16 + lg * 4;
  const int bq = m0 >> 12, s = m0 & 4095;
  #pragma unroll
  for (int nt = 0; nt < 16; nt++) {
    const int n = nt * 16 + l15;      // 0..255 within panel
    const float bv = bias[y * 256 + n];
    if (y == 0) {                     // Q (s>=2048 guaranteed by grid)
      const int ks = n >> 4, h2 = (n >> 3) & 1, e = n & 7;
      #pragma unroll
      for (int rr = 0; rr < 4; rr++) {
        const int qrow = bq * 2048 + (s - 2048) + rr;
        Qo[(size_t)(qrow >> 5) * 8192 + ks * 512 +
           ((qrow & 31) + 32 * h2) * 8 + e] =
            (bf16)((acc[nt][rr] + bv) * 0.0625f);
      }
    } else if (y == 1) {              // K
      const int d = n;
      const int ks = d >> 4, h2 = (d >> 3) & 1, e = d & 7;
      const size_t tb = (size_t)(bq * 128 + (s >> 5)) * 16384;
      #pragma unroll
      for (int rr = 0; rr < 4; rr++)
        KVo[tb + ks * 512 + (((s & 31) + rr) + 32 * h2) * 8 + e] =
            (bf16)(acc[nt][rr] + bv);
    } else {                          // V
      const int d = n;
      const int kv32 = s & 31;
      const int sidx = kv32 >> 4, h2 = (kv32 >> 3) & 1, e0 = kv32 & 7;
      bf16x4 st = { (bf16)(acc[nt][0] + bv), (bf16)(acc[nt][1] + bv),
                    (bf16)(acc[nt][2] + bv), (bf16)(acc[nt][3] + bv) };
      *(bf16x4*)(KVo + (size_t)(bq * 128 + (s >> 5)) * 16384 + 8192 +
                 (sidx * 8 + (d >> 5)) * 512 + ((d & 31) + 32 * h2) * 8 + e0) = st;
    }
  }
}

// ---------------------------------------------------------------------------
// flash attention (R7-verified, 52.8 us): 32x32x16 MFMA, q=32/wave, 4 waves.
// KV-split 8 -> 512 blocks. Fragment-ordered global K/V -> linear
// global_load_lds staging (dbuf), conflict-free lane-linear ds_read_b128.
// Swapped QK^T (S^T = mfma(K,Q)); P B-frags via pack + shfl_xor(32) exchange.
// ---------------------------------------------------------------------------
__global__ __launch_bounds__(256, 2) void attn_kernel(
    const bf16* __restrict__ Qp, const bf16* __restrict__ KVp,
    bf16* __restrict__ Opart, float* __restrict__ ml)
{
  const int id = blockIdx.x;
  const int c = id & 7;            // kv chunk -> XCD affinity (id%8)
  const int b = (id >> 3) & 3;     // batch
  const int qb = id >> 5;          // q block 0..15
  const int tid = threadIdx.x;
  const int lane = tid & 63, w = tid >> 6;
  const int l31 = lane & 31, hi = lane >> 5;

  __shared__ bf16 lds[2][16384];   // [buf][ K frags 0..8191 | V frags 8192.. ]

  const int qg = b * 64 + qb * 4 + w;
  const bf16* qbase = Qp + (size_t)qg * 8192 + lane * 8;
  bf16x8 qf[16];
  #pragma unroll
  for (int ks = 0; ks < 16; ks++)
    qf[ks] = *(const bf16x8*)(qbase + ks * 512);

  const bf16* kvtile0 = KVp + (size_t)(b * 128 + c * 16) * 16384;

  auto stage = [&](int t) {
    const char* g = (const char*)(kvtile0 + (size_t)t * 16384) + w * 8192 + lane * 16;
    char* l = (char*)&lds[t & 1][0] + w * 8192;
    #pragma unroll
    for (int j = 0; j < 8; j++)
      gload_lds16(g + j * 1024, l + j * 1024);
  };
  stage(0);

  f32x16 o[8] = {};                // O^T[d][q]: q = l31, d = dg*32+8*(r>>2)+4*hi+(r&3)
  float m_run = -1e30f, l_run = 0.f;

  for (int t = 0; t < 16; t++) {
    __syncthreads();               // tile t landed; buf^1 free
    if (t + 1 < 16) stage(t + 1);
    const bf16* kbuf = &lds[t & 1][0];
    const bf16* vbuf = kbuf + 8192;

    f32x16 p = {};
    __builtin_amdgcn_s_setprio(1);
    #pragma unroll
    for (int ks = 0; ks < 16; ks++) {
      bf16x8 kf = *(const bf16x8*)(kbuf + ks * 512 + lane * 8);
      p = MFMA32(kf, qf[ks], p);
    }
    __builtin_amdgcn_s_setprio(0);

    float mt = fmaxf(p[0], p[1]);
    #pragma unroll
    for (int i = 2; i < 16; i++) mt = fmaxf(mt, p[i]);
    mt = fmaxf(mt, __shfl_xor(mt, 32));
    if (!__all(mt <= m_run + 8.f)) {   // defer-max (T13)
      const float m_new = fmaxf(m_run, mt);
      const float alpha = __expf(m_run - m_new);
      l_run *= alpha;
      #pragma unroll
      for (int i = 0; i < 8; i++)
        #pragma unroll
        for (int j = 0; j < 16; j++) o[i][j] *= alpha;
      m_run = m_new;
    }
    float ps = 0.f;
    #pragma unroll
    for (int i = 0; i < 16; i++) { p[i] = __expf(p[i] - m_run); ps += p[i]; }
    ps += __shfl_xor(ps, 32);
    l_run += ps;

    // P -> B-frags (verified mapping)
    unsigned u[8], xp[8];
    #pragma unroll
    for (int i = 0; i < 8; i++) u[i] = packbf(p[2 * i], p[2 * i + 1]);
    #pragma unroll
    for (int i = 0; i < 8; i++)
      xp[i] = (unsigned)__shfl_xor((int)u[i], 32);
    const u32x4 w0 = hi ? (u32x4){xp[2], xp[3], u[2], u[3]}
                        : (u32x4){u[0], u[1], xp[0], xp[1]};
    const u32x4 w1 = hi ? (u32x4){xp[6], xp[7], u[6], u[7]}
                        : (u32x4){u[4], u[5], xp[4], xp[5]};
    const bf16x8 pf0 = __builtin_bit_cast(bf16x8, w0);
    const bf16x8 pf1 = __builtin_bit_cast(bf16x8, w1);

    __builtin_amdgcn_s_setprio(1);
    #pragma unroll
    for (int dg = 0; dg < 8; dg++) {
      bf16x8 v0 = *(const bf16x8*)(vbuf + dg * 512 + lane * 8);
      o[dg] = MFMA32(v0, pf0, o[dg]);
      bf16x8 v1 = *(const bf16x8*)(vbuf + (8 + dg) * 512 + lane * 8);
      o[dg] = MFMA32(v1, pf1, o[dg]);
    }
    __builtin_amdgcn_s_setprio(0);
  }

  const int q = b * 2048 + qb * 128 + w * 32 + l31;
  bf16* ob = Opart + ((size_t)c * 8192 + q) * 256;
  #pragma unroll
  for (int dg = 0; dg < 8; dg++) {
    #pragma unroll
    for (int r4 = 0; r4 < 4; r4++) {
      const int d = dg * 32 + r4 * 8 + hi * 4;
      bf16x4 st = { (bf16)o[dg][r4 * 4 + 0], (bf16)o[dg][r4 * 4 + 1],
                    (bf16)o[dg][r4 * 4 + 2], (bf16)o[dg][r4 * 4 + 3] };
      *(bf16x4*)(ob + d) = st;
    }
  }
  if (hi == 0) {
    float2 v = { m_run, l_run };
    *(float2*)(ml + ((size_t)c * 8192 + q) * 2) = v;
  }
}

// ---------------------------------------------------------------------------
// fused combine + out-proj (R12-verified): combine(Opart, ml) -> Alds
// (32x256, XOR-swz), then C = A @ Woutt^T + bout; W dbuf via global_load_lds.
// ---------------------------------------------------------------------------
__global__ __launch_bounds__(256) void out_kernel(
    const bf16* __restrict__ Opart, const float* __restrict__ ml,
    const bf16* __restrict__ Woutt, const float* __restrict__ bout,
    float* __restrict__ out)
{
  const int bm = blockIdx.x * 32;   // 256 blocks
  const int tid = threadIdx.x;
  const int lane = tid & 63, w = tid >> 6;
  const int l15 = lane & 15, lg = lane >> 4;

  alignas(16) __shared__ bf16 Alds[32 * 256];     // 16 KB, swz ^((row&7)<<4)
  alignas(16) __shared__ bf16 Wlds[2][256 * 32];  // 2 x 16 KB dbuf

  auto stageW = [&](int k0) {
    #pragma unroll
    for (int jj = 0; jj < 4; jj++) {
      int j = w * 4 + jj;                    // 16 x 1KB instrs
      int row = j * 16 + (lane >> 2);
      int chunk = (lane & 3) ^ ((row >> 1) & 3);
      const bf16* g = Woutt + (size_t)row * 256 + k0 * 32 + chunk * 8;
      gload_lds16(g, (char*)&Wlds[k0 & 1][0] + j * 1024);
    }
  };
  stageW(0);

  // combine 8 partials -> Alds
  #pragma unroll
  for (int ch = 0; ch < 4; ch++) {
    const int idx = ch * 256 + tid;
    const int row = idx >> 5;
    const int dc = (idx & 31) << 3;
    const int q = bm + row;
    float ms[8], ls[8], M = -1e30f;
    #pragma unroll
    for (int s = 0; s < 8; s++) {
      float2 v = *(const float2*)(ml + ((size_t)s * 8192 + q) * 2);
      ms[s] = v.x; ls[s] = v.y;
      M = fmaxf(M, v.x);
    }
    float L = 0.f, acc[8] = {};
    #pragma unroll
    for (int s = 0; s < 8; s++) {
      const float wgt = __expf(ms[s] - M);
      L += ls[s] * wgt;
      bf16x8 v = *(const bf16x8*)(Opart + ((size_t)s * 8192 + q) * 256 + dc);
      #pragma unroll
      for (int j = 0; j < 8; j++) acc[j] += wgt * (float)v[j];
    }
    const float inv = 1.f / L;
    bf16x8 st;
    #pragma unroll
    for (int j = 0; j < 8; j++) st[j] = (bf16)(acc[j] * inv);
    *(bf16x8*)((char*)Alds + ((row * 512 + dc * 2) ^ ((row & 7) << 4))) = st;
  }
  __syncthreads();   // Alds written, W(0) landed

  f32x4 acc[8] = {};
  for (int k0 = 0; k0 < 8; k0++) {
    if (k0 + 1 < 8) stageW(k0 + 1);
    const bf16* wbuf = &Wlds[k0 & 1][0];
    const int arow = (w & 1) * 16 + l15;
    bf16x8 afr = *(const bf16x8*)((char*)Alds +
        ((arow * 512 + k0 * 64 + lg * 16) ^ ((arow & 7) << 4)));
    #pragma unroll
    for (int nt = 0; nt < 8; nt++) {
      const int wrow = (w >> 1) * 128 + nt * 16 + l15;
      bf16x8 bfr = *(const bf16x8*)((char*)wbuf +
          (((wrow << 6) + (lg << 4)) ^ (((wrow >> 1) & 3) << 4)));
      acc[nt] = MFMA16(afr, bfr, acc[nt]);
    }
    __syncthreads();   // W(k0+1) landed; buf reads done before overwrite
  }

  #pragma unroll
  for (int nt = 0; nt < 8; nt++) {
    const int n = (w >> 1) * 128 + nt * 16 + l15;
    const float bvv = bout[n];
    const int m0 = bm + (w & 1) * 16 + lg * 4;
    #pragma unroll
    for (int r = 0; r < 4; r++)
      out[(size_t)(m0 + r) * 256 + n] = acc[nt][r] + bvv;
  }
}

// ---------------------------------------------------------------------------
extern "C" void kernel_launch(void* const* d_in, const int* in_sizes, int n_in,
                              void* d_out, int out_size, void* d_ws, size_t ws_size,
                              hipStream_t stream) {
  const float* x    = (const float*)d_in[0];
  const float* px   = (const float*)d_in[1];
  const float* Wqkv = (const float*)d_in[2];
  const float* bqkv = (const float*)d_in[3];
  const float* Wout = (const float*)d_in[4];
  const float* bout = (const float*)d_in[5];
  float* out = (float*)d_out;

  char* ws = (char*)d_ws;
  bf16* Qp    = (bf16*)(ws);                    //  4 MB frag-ordered Q (*1/16)
  bf16* KVp   = (bf16*)(ws + 4194304);          // 16 MB frag-ordered K|V tiles
  bf16* Woutt = (bf16*)(ws + 20971520);         // 128 KB
  bf16* Wqkvt = (bf16*)(ws + 21102592);         // 384 KB
  float* ml   = (float*)(ws + 21495808);        // 512 KB [8][8192][2]
  bf16* Opart = (bf16*)(ws + 22020096);         // 32 MB [8][8192][256]

  prep_w_kernel<<<dim3(128), dim3(256), 0, stream>>>(Wqkv, Wout, Wqkvt, Woutt);
  gemm_qkv_kernel<<<dim3(640), dim3(256), 0, stream>>>(
      x, px, Wqkvt, bqkv, Qp, KVp);
  attn_kernel<<<dim3(512), dim3(256), 0, stream>>>(Qp, KVp, Opart, ml);
  out_kernel<<<dim3(256), dim3(256), 0, stream>>>(Opart, ml, Woutt, bout, out);
}